// Round 1
// baseline (319.370 us; speedup 1.0000x reference)
//
#include <hip/hip_runtime.h>

// Problem constants
#define NN   4096      // H*W
#define CC   64        // C
#define C2   32        // C/2
#define BB   2         // batch
#define NSEG 8         // k-loop split for parallelism
#define KSEG (NN / NSEG)

// Workspace layout (floats)
//   q1: [B][N]        @ 0
//   k1: [B][N]        @ 8192
//   q2: [B][N]        @ 16384
//   k2: [B][N]        @ 24576
//   v1: [B][32][N]    @ 32768
//   v2: [B][32][N]    @ 294912
//   p : [2][NSEG][B][32][N] @ 557056   (partial outputs, both branches)
#define WS_Q1 0
#define WS_K1 8192
#define WS_Q2 16384
#define WS_K2 24576
#define WS_V1 32768
#define WS_V2 294912
#define WS_P  557056

// ---------------------------------------------------------------------------
// Stage A: 6 projections. thread = (b, proj, n). 32 accumulators per thread.
// q-projections reduce with max (branch1) / mean (branch2); v stored full.
// ---------------------------------------------------------------------------
__global__ __launch_bounds__(256) void proj_kernel(
    const float* __restrict__ x1, const float* __restrict__ x2,
    const float* __restrict__ wq1, const float* __restrict__ bq1,
    const float* __restrict__ wk1, const float* __restrict__ bk1,
    const float* __restrict__ wv1, const float* __restrict__ bv1,
    const float* __restrict__ wq2, const float* __restrict__ bq2,
    const float* __restrict__ wk2, const float* __restrict__ bk2,
    const float* __restrict__ wv2, const float* __restrict__ bv2,
    float* __restrict__ ws)
{
    const int n = blockIdx.x * 256 + threadIdx.x;
    const int p = blockIdx.y;   // 0..5
    const int b = blockIdx.z;   // 0..1

    const float* x; const float* w; const float* bias;
    int mode; float* dst;
    switch (p) {
      case 0: x = x1; w = wq1; bias = bq1; mode = 0; dst = ws + WS_Q1; break;
      case 1: x = x1; w = wk1; bias = bk1; mode = 0; dst = ws + WS_K1; break;
      case 2: x = x1; w = wv1; bias = bv1; mode = 2; dst = ws + WS_V1; break;
      case 3: x = x2; w = wq2; bias = bq2; mode = 1; dst = ws + WS_Q2; break;
      case 4: x = x2; w = wk2; bias = bk2; mode = 1; dst = ws + WS_K2; break;
      default:x = x2; w = wv2; bias = bv2; mode = 2; dst = ws + WS_V2; break;
    }

    float acc[C2];
    #pragma unroll
    for (int o = 0; o < C2; ++o) acc[o] = 0.0f;

    const float* xb = x + (size_t)b * CC * NN + n;
    for (int c = 0; c < CC; ++c) {
        const float xv = xb[(size_t)c * NN];     // coalesced across lanes
        #pragma unroll
        for (int o = 0; o < C2; ++o)
            acc[o] += w[o * CC + c] * xv;        // wave-uniform weight
    }
    #pragma unroll
    for (int o = 0; o < C2; ++o) acc[o] += bias[o];

    if (mode == 2) {            // store v
        #pragma unroll
        for (int o = 0; o < C2; ++o)
            dst[((size_t)b * C2 + o) * NN + n] = acc[o];
    } else if (mode == 0) {     // channel max
        float r = acc[0];
        #pragma unroll
        for (int o = 1; o < C2; ++o) r = fmaxf(r, acc[o]);
        dst[(size_t)b * NN + n] = r;
    } else {                    // channel mean
        float r = 0.0f;
        #pragma unroll
        for (int o = 0; o < C2; ++o) r += acc[o];
        dst[(size_t)b * NN + n] = r * (1.0f / C2);
    }
}

// ---------------------------------------------------------------------------
// Stage B: out_pre[b,c,m] = sum_k v[c,k] * g(q[m]*k[k]) over a k-segment.
// branch0: v=v1, q=q1, kvec=k2, g = 1-sigmoid = 1/(1+exp(+e))
// branch1: v=v2, q=q2, kvec=k1, g =   sigmoid = 1/(1+exp(-e))
// thread = (b, branch, seg, m); 32 fp32 accumulators; k/v loads wave-uniform.
// ---------------------------------------------------------------------------
__global__ __launch_bounds__(256) void attn_kernel(float* __restrict__ ws)
{
    const int m      = blockIdx.x * 256 + threadIdx.x;
    const int seg    = blockIdx.y;          // 0..NSEG-1
    const int bz     = blockIdx.z;          // 0..3
    const int b      = bz >> 1;
    const int branch = bz & 1;

    const float* q;  const float* kvec; const float* v; float sgn;
    if (branch == 0) { q = ws + WS_Q1; kvec = ws + WS_K2; v = ws + WS_V1; sgn =  1.0f; }
    else             { q = ws + WS_Q2; kvec = ws + WS_K1; v = ws + WS_V2; sgn = -1.0f; }

    const float qv = q[(size_t)b * NN + m];
    const float4* v4 = (const float4*)(v + (size_t)b * C2 * NN);
    const float4* k4 = (const float4*)(kvec + (size_t)b * NN);

    float acc[C2];
    #pragma unroll
    for (int c = 0; c < C2; ++c) acc[c] = 0.0f;

    const int kt0 = seg * (KSEG / 4);
    for (int kt = kt0; kt < kt0 + KSEG / 4; ++kt) {
        const float4 kk = k4[kt];           // wave-uniform
        const float s0 = __builtin_amdgcn_rcpf(1.0f + __expf(sgn * (qv * kk.x)));
        const float s1 = __builtin_amdgcn_rcpf(1.0f + __expf(sgn * (qv * kk.y)));
        const float s2 = __builtin_amdgcn_rcpf(1.0f + __expf(sgn * (qv * kk.z)));
        const float s3 = __builtin_amdgcn_rcpf(1.0f + __expf(sgn * (qv * kk.w)));
        #pragma unroll
        for (int c = 0; c < C2; ++c) {
            const float4 vv = v4[(size_t)c * (NN / 4) + kt];   // wave-uniform
            acc[c] += vv.x * s0 + vv.y * s1 + vv.z * s2 + vv.w * s3;
        }
    }

    float* pout = ws + WS_P
                + (((size_t)(branch * NSEG + seg) * BB + b) * C2) * NN + m;
    #pragma unroll
    for (int c = 0; c < C2; ++c)
        pout[(size_t)c * NN] = acc[c];      // coalesced over m
}

// ---------------------------------------------------------------------------
// Stage C: reduce NSEG partials, apply 1x1 conv (wc), bias, gamma, residual.
// branch0 -> out1 = x1 + gamma1 * (wc2 @ s + bc2), written at d_out[0]
// branch1 -> out2 = x2 + gamma2 * (wc1 @ s + bc1), written at d_out[B*C*N]
// ---------------------------------------------------------------------------
__global__ __launch_bounds__(256) void out_kernel(
    const float* __restrict__ x1, const float* __restrict__ x2,
    const float* __restrict__ wc1, const float* __restrict__ bc1,
    const float* __restrict__ wc2, const float* __restrict__ bc2,
    const float* __restrict__ g1,  const float* __restrict__ g2,
    const float* __restrict__ ws,  float* __restrict__ out)
{
    const int m      = blockIdx.x * 256 + threadIdx.x;
    const int b      = blockIdx.y >> 1;
    const int branch = blockIdx.y & 1;

    const float* w; const float* bias; const float* x; float gamma; float* o;
    if (branch == 0) { w = wc2; bias = bc2; x = x1; gamma = g1[0]; o = out; }
    else             { w = wc1; bias = bc1; x = x2; gamma = g2[0]; o = out + (size_t)BB * CC * NN; }

    // sum partials over segments
    float s[C2];
    const float* p = ws + WS_P + (size_t)branch * NSEG * BB * C2 * NN;
    #pragma unroll
    for (int c = 0; c < C2; ++c) {
        float t = 0.0f;
        #pragma unroll
        for (int seg = 0; seg < NSEG; ++seg)
            t += p[(((size_t)seg * BB + b) * C2 + c) * NN + m];
        s[c] = t;
    }

    for (int co = 0; co < CC; ++co) {
        float a = bias[co];
        #pragma unroll
        for (int c = 0; c < C2; ++c)
            a += w[co * C2 + c] * s[c];      // wave-uniform weight
        const size_t idx = ((size_t)b * CC + co) * NN + m;
        o[idx] = x[idx] + gamma * a;
    }
}

extern "C" void kernel_launch(void* const* d_in, const int* in_sizes, int n_in,
                              void* d_out, int out_size, void* d_ws, size_t ws_size,
                              hipStream_t stream)
{
    const float* x1  = (const float*)d_in[0];
    const float* x2  = (const float*)d_in[1];
    const float* wq1 = (const float*)d_in[2];
    const float* bq1 = (const float*)d_in[3];
    const float* wk1 = (const float*)d_in[4];
    const float* bk1 = (const float*)d_in[5];
    const float* wv1 = (const float*)d_in[6];
    const float* bv1 = (const float*)d_in[7];
    const float* wc1 = (const float*)d_in[8];
    const float* bc1 = (const float*)d_in[9];
    const float* wq2 = (const float*)d_in[10];
    const float* bq2 = (const float*)d_in[11];
    const float* wk2 = (const float*)d_in[12];
    const float* bk2 = (const float*)d_in[13];
    const float* wv2 = (const float*)d_in[14];
    const float* bv2 = (const float*)d_in[15];
    const float* wc2 = (const float*)d_in[16];
    const float* bc2 = (const float*)d_in[17];
    const float* g1  = (const float*)d_in[18];
    const float* g2  = (const float*)d_in[19];

    float* ws  = (float*)d_ws;
    float* out = (float*)d_out;

    proj_kernel<<<dim3(NN / 256, 6, BB), 256, 0, stream>>>(
        x1, x2, wq1, bq1, wk1, bk1, wv1, bv1,
        wq2, bq2, wk2, bk2, wv2, bv2, ws);

    attn_kernel<<<dim3(NN / 256, NSEG, BB * 2), 256, 0, stream>>>(ws);

    out_kernel<<<dim3(NN / 256, BB * 2), 256, 0, stream>>>(
        x1, x2, wc1, bc1, wc2, bc2, g1, g2, ws, out);
}

// Round 2
// 281.108 us; speedup vs baseline: 1.1361x; 1.1361x over previous
//
#include <hip/hip_runtime.h>

// Problem constants
#define NN 4096
#define CC 64
#define C2 32
#define BB 2

// Workspace layout (float offsets)
#define WS_Q1 0
#define WS_K1 8192
#define WS_Q2 16384
#define WS_K2 24576
#define WS_V1 32768
#define WS_V2 294912
#define WS_P  557056   // partials: [branch][seg][b][c][m]

typedef __attribute__((address_space(1))) const unsigned int GUI;
typedef __attribute__((address_space(3))) unsigned int LUI;

__device__ __forceinline__ void glds16(const float* g, float* l) {
    __builtin_amdgcn_global_load_lds((GUI*)g, (LUI*)l, 16, 0, 0);
}

// ---------------------------------------------------------------------------
// Stage A: 6 projections (unchanged from r1 — not the bottleneck).
// ---------------------------------------------------------------------------
__global__ __launch_bounds__(256) void proj_kernel(
    const float* __restrict__ x1, const float* __restrict__ x2,
    const float* __restrict__ wq1, const float* __restrict__ bq1,
    const float* __restrict__ wk1, const float* __restrict__ bk1,
    const float* __restrict__ wv1, const float* __restrict__ bv1,
    const float* __restrict__ wq2, const float* __restrict__ bq2,
    const float* __restrict__ wk2, const float* __restrict__ bk2,
    const float* __restrict__ wv2, const float* __restrict__ bv2,
    float* __restrict__ ws)
{
    const int n = blockIdx.x * 256 + threadIdx.x;
    const int p = blockIdx.y;
    const int b = blockIdx.z;

    const float* x; const float* w; const float* bias;
    int mode; float* dst;
    switch (p) {
      case 0: x = x1; w = wq1; bias = bq1; mode = 0; dst = ws + WS_Q1; break;
      case 1: x = x1; w = wk1; bias = bk1; mode = 0; dst = ws + WS_K1; break;
      case 2: x = x1; w = wv1; bias = bv1; mode = 2; dst = ws + WS_V1; break;
      case 3: x = x2; w = wq2; bias = bq2; mode = 1; dst = ws + WS_Q2; break;
      case 4: x = x2; w = wk2; bias = bk2; mode = 1; dst = ws + WS_K2; break;
      default:x = x2; w = wv2; bias = bv2; mode = 2; dst = ws + WS_V2; break;
    }

    float acc[C2];
    #pragma unroll
    for (int o = 0; o < C2; ++o) acc[o] = 0.0f;

    const float* xb = x + (size_t)b * CC * NN + n;
    for (int c = 0; c < CC; ++c) {
        const float xv = xb[(size_t)c * NN];
        #pragma unroll
        for (int o = 0; o < C2; ++o)
            acc[o] += w[o * CC + c] * xv;
    }
    #pragma unroll
    for (int o = 0; o < C2; ++o) acc[o] += bias[o];

    if (mode == 2) {
        #pragma unroll
        for (int o = 0; o < C2; ++o)
            dst[((size_t)b * C2 + o) * NN + n] = acc[o];
    } else if (mode == 0) {
        float r = acc[0];
        #pragma unroll
        for (int o = 1; o < C2; ++o) r = fmaxf(r, acc[o]);
        dst[(size_t)b * NN + n] = r;
    } else {
        float r = 0.0f;
        #pragma unroll
        for (int o = 0; o < C2; ++o) r += acc[o];
        dst[(size_t)b * NN + n] = r * (1.0f / C2);
    }
}

// ---------------------------------------------------------------------------
// Stage B: out_pre[b,c,m] = sum_k v[c,k] * g(q[m]*k[k]) over one k-segment.
// Block = 4 waves, m-tile of 1024 (4 m per thread), v+k segment staged in LDS.
// All LDS reads are wave-broadcast (same address) -> conflict-free.
// branch0: g = 1-sigmoid(x) = 1/(1+exp(+x));  branch1: g = sigmoid(x).
// ---------------------------------------------------------------------------
template<int KSEG>
__global__ __launch_bounds__(256, 1) void attn_kernel(
    const float* __restrict__ q1, const float* __restrict__ k1,
    const float* __restrict__ q2, const float* __restrict__ k2,
    const float* __restrict__ v1, const float* __restrict__ v2,
    float* __restrict__ pout)
{
    constexpr int NSEG = NN / KSEG;
    constexpr int KQ   = KSEG / 4;           // float4 per LDS row
    constexpr int KSH  = (KSEG == 256) ? 6 : 7;  // log2(KQ)
    constexpr int ROUNDS = (C2 * KSEG / 4) / 256;

    __shared__ float vbuf[C2 * KSEG];
    __shared__ float kbuf[KSEG];

    const int tid    = threadIdx.x;
    const int seg    = blockIdx.y;
    const int bz     = blockIdx.z;
    const int b      = bz >> 1;
    const int branch = bz & 1;
    const int m0     = blockIdx.x * 1024;
    const int k0     = seg * KSEG;

    const float* q; const float* kv; const float* v; float sl2e;
    if (branch == 0) { q = q1; kv = k2; v = v1; sl2e =  1.44269504089f; }
    else             { q = q2; kv = k1; v = v2; sl2e = -1.44269504089f; }

    // stage k segment (plain load + ds_write, once)
    if (tid * 4 < KSEG) {
        const float4 t = *(const float4*)(kv + (size_t)b * NN + k0 + tid * 4);
        *(float4*)(kbuf + tid * 4) = t;
    }
    // stage v segment via global_load_lds width 16 (linear LDS dest)
    {
        const float* vb = v + (size_t)b * C2 * NN + k0;
        #pragma unroll
        for (int r = 0; r < ROUNDS; ++r) {
            const int f = r * 256 + tid;         // float4 index in [c][k] tile
            const int c = f >> KSH;
            const int j = f & (KQ - 1);
            glds16(vb + (size_t)c * NN + j * 4, vbuf + f * 4);
        }
    }
    asm volatile("s_waitcnt vmcnt(0)" ::: "memory");
    __syncthreads();

    // q values: 4 m's per thread, contiguous (m0 + tid*4 + r)
    const float4 q4 = *(const float4*)(q + (size_t)b * NN + m0 + tid * 4);
    const float sq[4] = { q4.x * sl2e, q4.y * sl2e, q4.z * sl2e, q4.w * sl2e };

    float acc[4][C2];
    #pragma unroll
    for (int r = 0; r < 4; ++r)
        #pragma unroll
        for (int c = 0; c < C2; ++c) acc[r][c] = 0.0f;

    for (int g = 0; g < KQ; ++g) {
        const float4 kk = *(const float4*)(kbuf + g * 4);
        float s[4][4];
        #pragma unroll
        for (int r = 0; r < 4; ++r) {
            s[r][0] = __builtin_amdgcn_rcpf(1.0f + __builtin_amdgcn_exp2f(sq[r] * kk.x));
            s[r][1] = __builtin_amdgcn_rcpf(1.0f + __builtin_amdgcn_exp2f(sq[r] * kk.y));
            s[r][2] = __builtin_amdgcn_rcpf(1.0f + __builtin_amdgcn_exp2f(sq[r] * kk.z));
            s[r][3] = __builtin_amdgcn_rcpf(1.0f + __builtin_amdgcn_exp2f(sq[r] * kk.w));
        }
        #pragma unroll
        for (int c = 0; c < C2; ++c) {
            const float4 vv = *(const float4*)(vbuf + c * KSEG + g * 4);  // broadcast
            #pragma unroll
            for (int r = 0; r < 4; ++r)
                acc[r][c] = fmaf(vv.x, s[r][0],
                            fmaf(vv.y, s[r][1],
                            fmaf(vv.z, s[r][2],
                            fmaf(vv.w, s[r][3], acc[r][c]))));
        }
    }

    // write partials: [branch][seg][b][c][m], coalesced float4 over m
    #pragma unroll
    for (int c = 0; c < C2; ++c) {
        float4 o;
        o.x = acc[0][c]; o.y = acc[1][c]; o.z = acc[2][c]; o.w = acc[3][c];
        *(float4*)(pout + (((size_t)(branch * NSEG + seg) * BB + b) * C2 + c) * NN
                        + m0 + tid * 4) = o;
    }
}

// ---------------------------------------------------------------------------
// Stage C: reduce nseg partials, apply output 1x1 conv, gamma, residual.
// branch0 -> out1 = x1 + g1*(wc2 @ s + bc2);  branch1 -> out2 = x2 + g2*(wc1 @ s + bc1)
// ---------------------------------------------------------------------------
__global__ __launch_bounds__(256) void out_kernel(
    const float* __restrict__ x1, const float* __restrict__ x2,
    const float* __restrict__ wc1, const float* __restrict__ bc1,
    const float* __restrict__ wc2, const float* __restrict__ bc2,
    const float* __restrict__ g1,  const float* __restrict__ g2,
    const float* __restrict__ ws,  float* __restrict__ out, int nseg)
{
    const int m      = blockIdx.x * 256 + threadIdx.x;
    const int b      = blockIdx.y >> 1;
    const int branch = blockIdx.y & 1;

    const float* w; const float* bias; const float* x; float gamma; float* o;
    if (branch == 0) { w = wc2; bias = bc2; x = x1; gamma = g1[0]; o = out; }
    else             { w = wc1; bias = bc1; x = x2; gamma = g2[0]; o = out + (size_t)BB * CC * NN; }

    float s[C2];
    const float* p = ws + WS_P + (size_t)branch * nseg * BB * C2 * NN;
    #pragma unroll
    for (int c = 0; c < C2; ++c) {
        float t = 0.0f;
        for (int seg = 0; seg < nseg; ++seg)
            t += p[(((size_t)seg * BB + b) * C2 + c) * NN + m];
        s[c] = t;
    }

    for (int co = 0; co < CC; ++co) {
        float a = bias[co];
        #pragma unroll
        for (int c = 0; c < C2; ++c)
            a += w[co * C2 + c] * s[c];
        const size_t idx = ((size_t)b * CC + co) * NN + m;
        o[idx] = x[idx] + gamma * a;
    }
}

extern "C" void kernel_launch(void* const* d_in, const int* in_sizes, int n_in,
                              void* d_out, int out_size, void* d_ws, size_t ws_size,
                              hipStream_t stream)
{
    const float* x1  = (const float*)d_in[0];
    const float* x2  = (const float*)d_in[1];
    const float* wq1 = (const float*)d_in[2];
    const float* bq1 = (const float*)d_in[3];
    const float* wk1 = (const float*)d_in[4];
    const float* bk1 = (const float*)d_in[5];
    const float* wv1 = (const float*)d_in[6];
    const float* bv1 = (const float*)d_in[7];
    const float* wc1 = (const float*)d_in[8];
    const float* bc1 = (const float*)d_in[9];
    const float* wq2 = (const float*)d_in[10];
    const float* bq2 = (const float*)d_in[11];
    const float* wk2 = (const float*)d_in[12];
    const float* bk2 = (const float*)d_in[13];
    const float* wv2 = (const float*)d_in[14];
    const float* bv2 = (const float*)d_in[15];
    const float* wc2 = (const float*)d_in[16];
    const float* bc2 = (const float*)d_in[17];
    const float* g1  = (const float*)d_in[18];
    const float* g2  = (const float*)d_in[19];

    float* ws  = (float*)d_ws;
    float* out = (float*)d_out;

    proj_kernel<<<dim3(NN / 256, 6, BB), 256, 0, stream>>>(
        x1, x2, wq1, bq1, wk1, bk1, wv1, bv1,
        wq2, bq2, wk2, bk2, wv2, bv2, ws);

    // nseg=16 needs (WS_P + 2*16*2*32*4096) floats = ~35.8 MB of workspace
    const size_t need16 = ((size_t)WS_P + 2ull * 16 * BB * C2 * NN) * 4ull;
    const int nseg = (ws_size >= need16) ? 16 : 8;

    const float* q1 = ws + WS_Q1; const float* k1 = ws + WS_K1;
    const float* q2 = ws + WS_Q2; const float* k2 = ws + WS_K2;
    const float* v1 = ws + WS_V1; const float* v2 = ws + WS_V2;
    float* pp = ws + WS_P;

    if (nseg == 16) {
        attn_kernel<256><<<dim3(NN / 1024, 16, BB * 2), 256, 0, stream>>>(
            q1, k1, q2, k2, v1, v2, pp);
    } else {
        attn_kernel<512><<<dim3(NN / 1024, 8, BB * 2), 256, 0, stream>>>(
            q1, k1, q2, k2, v1, v2, pp);
    }

    out_kernel<<<dim3(NN / 256, BB * 2), 256, 0, stream>>>(
        x1, x2, wc1, bc1, wc2, bc2, g1, g2, ws, out, nseg);
}

// Round 3
// 150.473 us; speedup vs baseline: 2.1224x; 1.8682x over previous
//
#include <hip/hip_runtime.h>

// Problem constants
#define NN 4096
#define CC 64
#define C2 32
#define BB 2

// Workspace layout (float offsets)
#define WS_Q1 0
#define WS_K1 8192
#define WS_Q2 16384
#define WS_K2 24576
#define WS_V1 32768
#define WS_V2 294912
#define WS_P  557056   // partials: [branch][seg][b][c][m]

typedef __attribute__((address_space(1))) const unsigned int GUI;
typedef __attribute__((address_space(3))) unsigned int LUI;

__device__ __forceinline__ void glds16(const float* g, float* l) {
    __builtin_amdgcn_global_load_lds((GUI*)g, (LUI*)l, 16, 0, 0);
}

// ---------------------------------------------------------------------------
// Stage A: 6 projections (unchanged — awaiting clean profile ranking).
// ---------------------------------------------------------------------------
__global__ __launch_bounds__(256) void proj_kernel(
    const float* __restrict__ x1, const float* __restrict__ x2,
    const float* __restrict__ wq1, const float* __restrict__ bq1,
    const float* __restrict__ wk1, const float* __restrict__ bk1,
    const float* __restrict__ wv1, const float* __restrict__ bv1,
    const float* __restrict__ wq2, const float* __restrict__ bq2,
    const float* __restrict__ wk2, const float* __restrict__ bk2,
    const float* __restrict__ wv2, const float* __restrict__ bv2,
    float* __restrict__ ws)
{
    const int n = blockIdx.x * 256 + threadIdx.x;
    const int p = blockIdx.y;
    const int b = blockIdx.z;

    const float* x; const float* w; const float* bias;
    int mode; float* dst;
    switch (p) {
      case 0: x = x1; w = wq1; bias = bq1; mode = 0; dst = ws + WS_Q1; break;
      case 1: x = x1; w = wk1; bias = bk1; mode = 0; dst = ws + WS_K1; break;
      case 2: x = x1; w = wv1; bias = bv1; mode = 2; dst = ws + WS_V1; break;
      case 3: x = x2; w = wq2; bias = bq2; mode = 1; dst = ws + WS_Q2; break;
      case 4: x = x2; w = wk2; bias = bk2; mode = 1; dst = ws + WS_K2; break;
      default:x = x2; w = wv2; bias = bv2; mode = 2; dst = ws + WS_V2; break;
    }

    float acc[C2];
    #pragma unroll
    for (int o = 0; o < C2; ++o) acc[o] = 0.0f;

    const float* xb = x + (size_t)b * CC * NN + n;
    for (int c = 0; c < CC; ++c) {
        const float xv = xb[(size_t)c * NN];
        #pragma unroll
        for (int o = 0; o < C2; ++o)
            acc[o] += w[o * CC + c] * xv;
    }
    #pragma unroll
    for (int o = 0; o < C2; ++o) acc[o] += bias[o];

    if (mode == 2) {
        #pragma unroll
        for (int o = 0; o < C2; ++o)
            dst[((size_t)b * C2 + o) * NN + n] = acc[o];
    } else if (mode == 0) {
        float r = acc[0];
        #pragma unroll
        for (int o = 1; o < C2; ++o) r = fmaxf(r, acc[o]);
        dst[(size_t)b * NN + n] = r;
    } else {
        float r = 0.0f;
        #pragma unroll
        for (int o = 0; o < C2; ++o) r += acc[o];
        dst[(size_t)b * NN + n] = r * (1.0f / C2);
    }
}

// ---------------------------------------------------------------------------
// Stage B: attn over one k-segment (unchanged from r2).
// ---------------------------------------------------------------------------
template<int KSEG>
__global__ __launch_bounds__(256, 1) void attn_kernel(
    const float* __restrict__ q1, const float* __restrict__ k1,
    const float* __restrict__ q2, const float* __restrict__ k2,
    const float* __restrict__ v1, const float* __restrict__ v2,
    float* __restrict__ pout)
{
    constexpr int NSEG = NN / KSEG;
    constexpr int KQ   = KSEG / 4;
    constexpr int KSH  = (KSEG == 256) ? 6 : 7;
    constexpr int ROUNDS = (C2 * KSEG / 4) / 256;

    __shared__ float vbuf[C2 * KSEG];
    __shared__ float kbuf[KSEG];

    const int tid    = threadIdx.x;
    const int seg    = blockIdx.y;
    const int bz     = blockIdx.z;
    const int b      = bz >> 1;
    const int branch = bz & 1;
    const int m0     = blockIdx.x * 1024;
    const int k0     = seg * KSEG;

    const float* q; const float* kv; const float* v; float sl2e;
    if (branch == 0) { q = q1; kv = k2; v = v1; sl2e =  1.44269504089f; }
    else             { q = q2; kv = k1; v = v2; sl2e = -1.44269504089f; }

    if (tid * 4 < KSEG) {
        const float4 t = *(const float4*)(kv + (size_t)b * NN + k0 + tid * 4);
        *(float4*)(kbuf + tid * 4) = t;
    }
    {
        const float* vb = v + (size_t)b * C2 * NN + k0;
        #pragma unroll
        for (int r = 0; r < ROUNDS; ++r) {
            const int f = r * 256 + tid;
            const int c = f >> KSH;
            const int j = f & ((KSEG / 4) - 1);
            glds16(vb + (size_t)c * NN + j * 4, vbuf + f * 4);
        }
    }
    asm volatile("s_waitcnt vmcnt(0)" ::: "memory");
    __syncthreads();

    const float4 q4 = *(const float4*)(q + (size_t)b * NN + m0 + tid * 4);
    const float sq[4] = { q4.x * sl2e, q4.y * sl2e, q4.z * sl2e, q4.w * sl2e };

    float acc[4][C2];
    #pragma unroll
    for (int r = 0; r < 4; ++r)
        #pragma unroll
        for (int c = 0; c < C2; ++c) acc[r][c] = 0.0f;

    for (int g = 0; g < KSEG / 4; ++g) {
        const float4 kk = *(const float4*)(kbuf + g * 4);
        float s[4][4];
        #pragma unroll
        for (int r = 0; r < 4; ++r) {
            s[r][0] = __builtin_amdgcn_rcpf(1.0f + __builtin_amdgcn_exp2f(sq[r] * kk.x));
            s[r][1] = __builtin_amdgcn_rcpf(1.0f + __builtin_amdgcn_exp2f(sq[r] * kk.y));
            s[r][2] = __builtin_amdgcn_rcpf(1.0f + __builtin_amdgcn_exp2f(sq[r] * kk.z));
            s[r][3] = __builtin_amdgcn_rcpf(1.0f + __builtin_amdgcn_exp2f(sq[r] * kk.w));
        }
        #pragma unroll
        for (int c = 0; c < C2; ++c) {
            const float4 vv = *(const float4*)(vbuf + c * KSEG + g * 4);
            #pragma unroll
            for (int r = 0; r < 4; ++r)
                acc[r][c] = fmaf(vv.x, s[r][0],
                            fmaf(vv.y, s[r][1],
                            fmaf(vv.z, s[r][2],
                            fmaf(vv.w, s[r][3], acc[r][c]))));
        }
    }

    #pragma unroll
    for (int c = 0; c < C2; ++c) {
        float4 o;
        o.x = acc[0][c]; o.y = acc[1][c]; o.z = acc[2][c]; o.w = acc[3][c];
        *(float4*)(pout + (((size_t)(branch * NSEG + seg) * BB + b) * C2 + c) * NN
                        + m0 + tid * 4) = o;
    }
}

// ---------------------------------------------------------------------------
// Stage C1: parallel segment reduction. One float4 of (branch,b,c,m) per
// thread; sums nseg partials and writes result IN-PLACE into the seg-0 slot.
// 512 blocks -> 8 waves/CU, 16 independent coalesced loads per thread.
// ---------------------------------------------------------------------------
__global__ __launch_bounds__(256) void reduce_kernel(float* __restrict__ p, int nseg)
{
    const int t      = blockIdx.x * 256 + threadIdx.x;   // 0 .. 131071
    const int m4     = t & 1023;
    const int c      = (t >> 10) & 31;
    const int b      = (t >> 15) & 1;
    const int branch = t >> 16;

    const size_t segstride = (size_t)BB * C2 * NN;
    const float* base = p + ((size_t)branch * nseg * BB + b) * C2 * NN
                          + (size_t)c * NN + m4 * 4;

    float4 acc = *(const float4*)base;
    for (int s = 1; s < nseg; ++s) {
        const float4 v = *(const float4*)(base + s * segstride);
        acc.x += v.x; acc.y += v.y; acc.z += v.z; acc.w += v.w;
    }
    *(float4*)(p + ((size_t)branch * nseg * BB + b) * C2 * NN
                 + (size_t)c * NN + m4 * 4) = acc;
}

// ---------------------------------------------------------------------------
// Stage C2: output 1x1 conv + gamma + residual, reading reduced s from the
// seg-0 slot. Grid (m-tiles, 4 co-groups, 4 (b,branch)) = 256 blocks.
// ---------------------------------------------------------------------------
__global__ __launch_bounds__(256) void conv_kernel(
    const float* __restrict__ x1, const float* __restrict__ x2,
    const float* __restrict__ wc1, const float* __restrict__ bc1,
    const float* __restrict__ wc2, const float* __restrict__ bc2,
    const float* __restrict__ g1,  const float* __restrict__ g2,
    const float* __restrict__ p,   float* __restrict__ out, int nseg)
{
    const int m      = blockIdx.x * 256 + threadIdx.x;
    const int co0    = blockIdx.y * 16;
    const int b      = blockIdx.z >> 1;
    const int branch = blockIdx.z & 1;

    const float* w; const float* bias; const float* x; float gamma; float* o;
    if (branch == 0) { w = wc2; bias = bc2; x = x1; gamma = g1[0]; o = out; }
    else             { w = wc1; bias = bc1; x = x2; gamma = g2[0]; o = out + (size_t)BB * CC * NN; }

    const float* sbase = p + ((size_t)branch * nseg * BB + b) * C2 * NN + m;
    float s[C2];
    #pragma unroll
    for (int c = 0; c < C2; ++c) s[c] = sbase[(size_t)c * NN];

    #pragma unroll
    for (int co = co0; co < co0 + 16; ++co) {
        float a = bias[co];
        #pragma unroll
        for (int c = 0; c < C2; ++c)
            a += w[co * C2 + c] * s[c];
        const size_t idx = ((size_t)b * CC + co) * NN + m;
        o[idx] = x[idx] + gamma * a;
    }
}

extern "C" void kernel_launch(void* const* d_in, const int* in_sizes, int n_in,
                              void* d_out, int out_size, void* d_ws, size_t ws_size,
                              hipStream_t stream)
{
    const float* x1  = (const float*)d_in[0];
    const float* x2  = (const float*)d_in[1];
    const float* wq1 = (const float*)d_in[2];
    const float* bq1 = (const float*)d_in[3];
    const float* wk1 = (const float*)d_in[4];
    const float* bk1 = (const float*)d_in[5];
    const float* wv1 = (const float*)d_in[6];
    const float* bv1 = (const float*)d_in[7];
    const float* wc1 = (const float*)d_in[8];
    const float* bc1 = (const float*)d_in[9];
    const float* wq2 = (const float*)d_in[10];
    const float* bq2 = (const float*)d_in[11];
    const float* wk2 = (const float*)d_in[12];
    const float* bk2 = (const float*)d_in[13];
    const float* wv2 = (const float*)d_in[14];
    const float* bv2 = (const float*)d_in[15];
    const float* wc2 = (const float*)d_in[16];
    const float* bc2 = (const float*)d_in[17];
    const float* g1  = (const float*)d_in[18];
    const float* g2  = (const float*)d_in[19];

    float* ws  = (float*)d_ws;
    float* out = (float*)d_out;

    proj_kernel<<<dim3(NN / 256, 6, BB), 256, 0, stream>>>(
        x1, x2, wq1, bq1, wk1, bk1, wv1, bv1,
        wq2, bq2, wk2, bk2, wv2, bv2, ws);

    const size_t need16 = ((size_t)WS_P + 2ull * 16 * BB * C2 * NN) * 4ull;
    const int nseg = (ws_size >= need16) ? 16 : 8;

    const float* q1 = ws + WS_Q1; const float* k1 = ws + WS_K1;
    const float* q2 = ws + WS_Q2; const float* k2 = ws + WS_K2;
    const float* v1 = ws + WS_V1; const float* v2 = ws + WS_V2;
    float* pp = ws + WS_P;

    if (nseg == 16) {
        attn_kernel<256><<<dim3(NN / 1024, 16, BB * 2), 256, 0, stream>>>(
            q1, k1, q2, k2, v1, v2, pp);
    } else {
        attn_kernel<512><<<dim3(NN / 1024, 8, BB * 2), 256, 0, stream>>>(
            q1, k1, q2, k2, v1, v2, pp);
    }

    reduce_kernel<<<dim3(512), 256, 0, stream>>>(pp, nseg);

    conv_kernel<<<dim3(NN / 256, 4, BB * 2), 256, 0, stream>>>(
        x1, x2, wc1, bc1, wc2, bc2, g1, g2, pp, out, nseg);
}

// Round 4
// 136.879 us; speedup vs baseline: 2.3332x; 1.0993x over previous
//
#include <hip/hip_runtime.h>

// Problem constants
#define NN 4096
#define CC 64
#define C2 32
#define BB 2

// Workspace layout (float offsets)
#define WS_Q1 0
#define WS_K1 8192
#define WS_Q2 16384
#define WS_K2 24576
#define WS_V1 32768
#define WS_V2 294912
#define WS_P  557056   // partials: [branch][seg][b][c][m]

typedef __attribute__((address_space(1))) const unsigned int GUI;
typedef __attribute__((address_space(3))) unsigned int LUI;

__device__ __forceinline__ void glds16(const float* g, float* l) {
    __builtin_amdgcn_global_load_lds((GUI*)g, (LUI*)l, 16, 0, 0);
}

// ---------------------------------------------------------------------------
// Stage A: 6 projections (unchanged).
// ---------------------------------------------------------------------------
__global__ __launch_bounds__(256) void proj_kernel(
    const float* __restrict__ x1, const float* __restrict__ x2,
    const float* __restrict__ wq1, const float* __restrict__ bq1,
    const float* __restrict__ wk1, const float* __restrict__ bk1,
    const float* __restrict__ wv1, const float* __restrict__ bv1,
    const float* __restrict__ wq2, const float* __restrict__ bq2,
    const float* __restrict__ wk2, const float* __restrict__ bk2,
    const float* __restrict__ wv2, const float* __restrict__ bv2,
    float* __restrict__ ws)
{
    const int n = blockIdx.x * 256 + threadIdx.x;
    const int p = blockIdx.y;
    const int b = blockIdx.z;

    const float* x; const float* w; const float* bias;
    int mode; float* dst;
    switch (p) {
      case 0: x = x1; w = wq1; bias = bq1; mode = 0; dst = ws + WS_Q1; break;
      case 1: x = x1; w = wk1; bias = bk1; mode = 0; dst = ws + WS_K1; break;
      case 2: x = x1; w = wv1; bias = bv1; mode = 2; dst = ws + WS_V1; break;
      case 3: x = x2; w = wq2; bias = bq2; mode = 1; dst = ws + WS_Q2; break;
      case 4: x = x2; w = wk2; bias = bk2; mode = 1; dst = ws + WS_K2; break;
      default:x = x2; w = wv2; bias = bv2; mode = 2; dst = ws + WS_V2; break;
    }

    float acc[C2];
    #pragma unroll
    for (int o = 0; o < C2; ++o) acc[o] = 0.0f;

    const float* xb = x + (size_t)b * CC * NN + n;
    for (int c = 0; c < CC; ++c) {
        const float xv = xb[(size_t)c * NN];
        #pragma unroll
        for (int o = 0; o < C2; ++o)
            acc[o] += w[o * CC + c] * xv;
    }
    #pragma unroll
    for (int o = 0; o < C2; ++o) acc[o] += bias[o];

    if (mode == 2) {
        #pragma unroll
        for (int o = 0; o < C2; ++o)
            dst[((size_t)b * C2 + o) * NN + n] = acc[o];
    } else if (mode == 0) {
        float r = acc[0];
        #pragma unroll
        for (int o = 1; o < C2; ++o) r = fmaxf(r, acc[o]);
        dst[(size_t)b * NN + n] = r;
    } else {
        float r = 0.0f;
        #pragma unroll
        for (int o = 0; o < C2; ++o) r += acc[o];
        dst[(size_t)b * NN + n] = r * (1.0f / C2);
    }
}

// ---------------------------------------------------------------------------
// Stage B: attn over one k-segment. M_PER=2 (acc[2][32]), m-tile = 512.
// Grid = 8 m-tiles x 16 seg x 4 (b,branch) = 512 blocks = 2 blocks/CU
// -> 8 waves/CU = 2 waves/SIMD for latency hiding (r3 had 1/SIMD, 34% VALU).
// ---------------------------------------------------------------------------
template<int KSEG>
__global__ __launch_bounds__(256, 2) void attn_kernel(
    const float* __restrict__ q1, const float* __restrict__ k1,
    const float* __restrict__ q2, const float* __restrict__ k2,
    const float* __restrict__ v1, const float* __restrict__ v2,
    float* __restrict__ pout)
{
    constexpr int NSEG = NN / KSEG;
    constexpr int KSH  = (KSEG == 256) ? 6 : 7;       // log2(KSEG/4)
    constexpr int ROUNDS = (C2 * KSEG / 4) / 256;

    __shared__ float vbuf[C2 * KSEG];
    __shared__ float kbuf[KSEG];

    const int tid    = threadIdx.x;
    const int seg    = blockIdx.y;
    const int bz     = blockIdx.z;
    const int b      = bz >> 1;
    const int branch = bz & 1;
    const int m0     = blockIdx.x * 512;
    const int k0     = seg * KSEG;

    const float* q; const float* kv; const float* v; float sl2e;
    if (branch == 0) { q = q1; kv = k2; v = v1; sl2e =  1.44269504089f; }
    else             { q = q2; kv = k1; v = v2; sl2e = -1.44269504089f; }

    if (tid * 4 < KSEG) {
        const float4 t = *(const float4*)(kv + (size_t)b * NN + k0 + tid * 4);
        *(float4*)(kbuf + tid * 4) = t;
    }
    {
        const float* vb = v + (size_t)b * C2 * NN + k0;
        #pragma unroll
        for (int r = 0; r < ROUNDS; ++r) {
            const int f = r * 256 + tid;
            const int c = f >> KSH;
            const int j = f & ((KSEG / 4) - 1);
            glds16(vb + (size_t)c * NN + j * 4, vbuf + f * 4);
        }
    }
    asm volatile("s_waitcnt vmcnt(0)" ::: "memory");
    __syncthreads();

    // 2 m's per thread, contiguous
    const float2 q2v = *(const float2*)(q + (size_t)b * NN + m0 + tid * 2);
    const float sq[2] = { q2v.x * sl2e, q2v.y * sl2e };

    float acc[2][C2];
    #pragma unroll
    for (int r = 0; r < 2; ++r)
        #pragma unroll
        for (int c = 0; c < C2; ++c) acc[r][c] = 0.0f;

    #pragma unroll 2
    for (int g = 0; g < KSEG / 4; ++g) {
        const float4 kk = *(const float4*)(kbuf + g * 4);
        float s[2][4];
        #pragma unroll
        for (int r = 0; r < 2; ++r) {
            s[r][0] = __builtin_amdgcn_rcpf(1.0f + __builtin_amdgcn_exp2f(sq[r] * kk.x));
            s[r][1] = __builtin_amdgcn_rcpf(1.0f + __builtin_amdgcn_exp2f(sq[r] * kk.y));
            s[r][2] = __builtin_amdgcn_rcpf(1.0f + __builtin_amdgcn_exp2f(sq[r] * kk.z));
            s[r][3] = __builtin_amdgcn_rcpf(1.0f + __builtin_amdgcn_exp2f(sq[r] * kk.w));
        }
        #pragma unroll
        for (int c = 0; c < C2; ++c) {
            const float4 vv = *(const float4*)(vbuf + c * KSEG + g * 4);  // broadcast
            #pragma unroll
            for (int r = 0; r < 2; ++r)
                acc[r][c] = fmaf(vv.x, s[r][0],
                            fmaf(vv.y, s[r][1],
                            fmaf(vv.z, s[r][2],
                            fmaf(vv.w, s[r][3], acc[r][c]))));
        }
    }

    #pragma unroll
    for (int c = 0; c < C2; ++c) {
        float2 o;
        o.x = acc[0][c]; o.y = acc[1][c];
        *(float2*)(pout + (((size_t)(branch * NSEG + seg) * BB + b) * C2 + c) * NN
                        + m0 + tid * 2) = o;
    }
}

// ---------------------------------------------------------------------------
// Stage C1: parallel segment reduction (unchanged).
// ---------------------------------------------------------------------------
__global__ __launch_bounds__(256) void reduce_kernel(float* __restrict__ p, int nseg)
{
    const int t      = blockIdx.x * 256 + threadIdx.x;
    const int m4     = t & 1023;
    const int c      = (t >> 10) & 31;
    const int b      = (t >> 15) & 1;
    const int branch = t >> 16;

    const size_t segstride = (size_t)BB * C2 * NN;
    const float* base = p + ((size_t)branch * nseg * BB + b) * C2 * NN
                          + (size_t)c * NN + m4 * 4;

    float4 acc = *(const float4*)base;
    for (int s = 1; s < nseg; ++s) {
        const float4 v = *(const float4*)(base + s * segstride);
        acc.x += v.x; acc.y += v.y; acc.z += v.z; acc.w += v.w;
    }
    *(float4*)(p + ((size_t)branch * nseg * BB + b) * C2 * NN
                 + (size_t)c * NN + m4 * 4) = acc;
}

// ---------------------------------------------------------------------------
// Stage C2: output conv + gamma + residual (unchanged).
// ---------------------------------------------------------------------------
__global__ __launch_bounds__(256) void conv_kernel(
    const float* __restrict__ x1, const float* __restrict__ x2,
    const float* __restrict__ wc1, const float* __restrict__ bc1,
    const float* __restrict__ wc2, const float* __restrict__ bc2,
    const float* __restrict__ g1,  const float* __restrict__ g2,
    const float* __restrict__ p,   float* __restrict__ out, int nseg)
{
    const int m      = blockIdx.x * 256 + threadIdx.x;
    const int co0    = blockIdx.y * 16;
    const int b      = blockIdx.z >> 1;
    const int branch = blockIdx.z & 1;

    const float* w; const float* bias; const float* x; float gamma; float* o;
    if (branch == 0) { w = wc2; bias = bc2; x = x1; gamma = g1[0]; o = out; }
    else             { w = wc1; bias = bc1; x = x2; gamma = g2[0]; o = out + (size_t)BB * CC * NN; }

    const float* sbase = p + ((size_t)branch * nseg * BB + b) * C2 * NN + m;
    float s[C2];
    #pragma unroll
    for (int c = 0; c < C2; ++c) s[c] = sbase[(size_t)c * NN];

    #pragma unroll
    for (int co = co0; co < co0 + 16; ++co) {
        float a = bias[co];
        #pragma unroll
        for (int c = 0; c < C2; ++c)
            a += w[co * C2 + c] * s[c];
        const size_t idx = ((size_t)b * CC + co) * NN + m;
        o[idx] = x[idx] + gamma * a;
    }
}

extern "C" void kernel_launch(void* const* d_in, const int* in_sizes, int n_in,
                              void* d_out, int out_size, void* d_ws, size_t ws_size,
                              hipStream_t stream)
{
    const float* x1  = (const float*)d_in[0];
    const float* x2  = (const float*)d_in[1];
    const float* wq1 = (const float*)d_in[2];
    const float* bq1 = (const float*)d_in[3];
    const float* wk1 = (const float*)d_in[4];
    const float* bk1 = (const float*)d_in[5];
    const float* wv1 = (const float*)d_in[6];
    const float* bv1 = (const float*)d_in[7];
    const float* wc1 = (const float*)d_in[8];
    const float* bc1 = (const float*)d_in[9];
    const float* wq2 = (const float*)d_in[10];
    const float* bq2 = (const float*)d_in[11];
    const float* wk2 = (const float*)d_in[12];
    const float* bk2 = (const float*)d_in[13];
    const float* wv2 = (const float*)d_in[14];
    const float* bv2 = (const float*)d_in[15];
    const float* wc2 = (const float*)d_in[16];
    const float* bc2 = (const float*)d_in[17];
    const float* g1  = (const float*)d_in[18];
    const float* g2  = (const float*)d_in[19];

    float* ws  = (float*)d_ws;
    float* out = (float*)d_out;

    proj_kernel<<<dim3(NN / 256, 6, BB), 256, 0, stream>>>(
        x1, x2, wq1, bq1, wk1, bk1, wv1, bv1,
        wq2, bq2, wk2, bk2, wv2, bv2, ws);

    const size_t need16 = ((size_t)WS_P + 2ull * 16 * BB * C2 * NN) * 4ull;
    const int nseg = (ws_size >= need16) ? 16 : 8;

    const float* q1 = ws + WS_Q1; const float* k1 = ws + WS_K1;
    const float* q2 = ws + WS_Q2; const float* k2 = ws + WS_K2;
    const float* v1 = ws + WS_V1; const float* v2 = ws + WS_V2;
    float* pp = ws + WS_P;

    if (nseg == 16) {
        attn_kernel<256><<<dim3(NN / 512, 16, BB * 2), 256, 0, stream>>>(
            q1, k1, q2, k2, v1, v2, pp);
    } else {
        attn_kernel<512><<<dim3(NN / 512, 8, BB * 2), 256, 0, stream>>>(
            q1, k1, q2, k2, v1, v2, pp);
    }

    reduce_kernel<<<dim3(512), 256, 0, stream>>>(pp, nseg);

    conv_kernel<<<dim3(NN / 256, 4, BB * 2), 256, 0, stream>>>(
        x1, x2, wc1, bc1, wc2, bc2, g1, g2, pp, out, nseg);
}

// Round 5
// 109.713 us; speedup vs baseline: 2.9109x; 1.2476x over previous
//
#include <hip/hip_runtime.h>

// Problem constants
#define NN 4096
#define CC 64
#define C2 32
#define BB 2

// Workspace layout (float offsets)
#define WS_Q1 0
#define WS_K1 8192
#define WS_Q2 16384
#define WS_K2 24576
#define WS_V1 32768
#define WS_V2 294912
#define WS_P  557056   // partials: [branch][seg][b][c][m]

typedef __attribute__((address_space(1))) const unsigned int GUI;
typedef __attribute__((address_space(3))) unsigned int LUI;

__device__ __forceinline__ void glds16(const float* g, float* l) {
    __builtin_amdgcn_global_load_lds((GUI*)g, (LUI*)l, 16, 0, 0);
}

// ---------------------------------------------------------------------------
// Stage A: 6 projections (unchanged).
// ---------------------------------------------------------------------------
__global__ __launch_bounds__(256) void proj_kernel(
    const float* __restrict__ x1, const float* __restrict__ x2,
    const float* __restrict__ wq1, const float* __restrict__ bq1,
    const float* __restrict__ wk1, const float* __restrict__ bk1,
    const float* __restrict__ wv1, const float* __restrict__ bv1,
    const float* __restrict__ wq2, const float* __restrict__ bq2,
    const float* __restrict__ wk2, const float* __restrict__ bk2,
    const float* __restrict__ wv2, const float* __restrict__ bv2,
    float* __restrict__ ws)
{
    const int n = blockIdx.x * 256 + threadIdx.x;
    const int p = blockIdx.y;
    const int b = blockIdx.z;

    const float* x; const float* w; const float* bias;
    int mode; float* dst;
    switch (p) {
      case 0: x = x1; w = wq1; bias = bq1; mode = 0; dst = ws + WS_Q1; break;
      case 1: x = x1; w = wk1; bias = bk1; mode = 0; dst = ws + WS_K1; break;
      case 2: x = x1; w = wv1; bias = bv1; mode = 2; dst = ws + WS_V1; break;
      case 3: x = x2; w = wq2; bias = bq2; mode = 1; dst = ws + WS_Q2; break;
      case 4: x = x2; w = wk2; bias = bk2; mode = 1; dst = ws + WS_K2; break;
      default:x = x2; w = wv2; bias = bv2; mode = 2; dst = ws + WS_V2; break;
    }

    float acc[C2];
    #pragma unroll
    for (int o = 0; o < C2; ++o) acc[o] = 0.0f;

    const float* xb = x + (size_t)b * CC * NN + n;
    for (int c = 0; c < CC; ++c) {
        const float xv = xb[(size_t)c * NN];
        #pragma unroll
        for (int o = 0; o < C2; ++o)
            acc[o] += w[o * CC + c] * xv;
    }
    #pragma unroll
    for (int o = 0; o < C2; ++o) acc[o] += bias[o];

    if (mode == 2) {
        #pragma unroll
        for (int o = 0; o < C2; ++o)
            dst[((size_t)b * C2 + o) * NN + n] = acc[o];
    } else if (mode == 0) {
        float r = acc[0];
        #pragma unroll
        for (int o = 1; o < C2; ++o) r = fmaxf(r, acc[o]);
        dst[(size_t)b * NN + n] = r;
    } else {
        float r = 0.0f;
        #pragma unroll
        for (int o = 0; o < C2; ++o) r += acc[o];
        dst[(size_t)b * NN + n] = r * (1.0f / C2);
    }
}

// ---------------------------------------------------------------------------
// Stage B: attn. M_PER=4 (acc[4][CPER]) so each ds_read_b128 of v feeds
// 16 FMAs instead of 8 (r4 was LDS-instruction-throughput bound at 33 reads
// per 256 FMA-lanes). Occupancy held at 2 blocks/CU via more segments
// (KSEG=128) or c-split (CPER=16).
//   grid: x = m-tiles (NN/1024), y = seg, z = chalf*4 + b*2 + branch
// ---------------------------------------------------------------------------
template<int KSEG, int CPER>
__global__ __launch_bounds__(256, 2) void attn_kernel(
    const float* __restrict__ q1, const float* __restrict__ k1,
    const float* __restrict__ q2, const float* __restrict__ k2,
    const float* __restrict__ v1, const float* __restrict__ v2,
    float* __restrict__ pout)
{
    constexpr int NSEG = NN / KSEG;
    constexpr int KQ   = KSEG / 4;
    constexpr int ROUNDS = (CPER * KSEG / 4) / 256;

    __shared__ float vbuf[CPER * KSEG];
    __shared__ float kbuf[KSEG];

    const int tid    = threadIdx.x;
    const int seg    = blockIdx.y;
    const int z      = blockIdx.z;
    const int branch = z & 1;
    const int b      = (z >> 1) & 1;
    const int c0     = (z >> 2) * CPER;
    const int m0     = blockIdx.x * 1024;
    const int k0     = seg * KSEG;

    const float* q; const float* kv; const float* v; float sl2e;
    if (branch == 0) { q = q1; kv = k2; v = v1; sl2e =  1.44269504089f; }
    else             { q = q2; kv = k1; v = v2; sl2e = -1.44269504089f; }

    // stage k segment
    if (tid * 4 < KSEG) {
        const float4 t = *(const float4*)(kv + (size_t)b * NN + k0 + tid * 4);
        *(float4*)(kbuf + tid * 4) = t;
    }
    // stage v rows [c0, c0+CPER) via global_load_lds (linear LDS dest)
    {
        const float* vb = v + ((size_t)b * C2 + c0) * NN + k0;
        #pragma unroll
        for (int r = 0; r < ROUNDS; ++r) {
            const int f = r * 256 + tid;       // float4 index in [CPER][KQ] tile
            const int c = f / KQ;
            const int j = f % KQ;
            glds16(vb + (size_t)c * NN + j * 4, vbuf + f * 4);
        }
    }
    asm volatile("s_waitcnt vmcnt(0)" ::: "memory");
    __syncthreads();

    // 4 m's per thread, contiguous
    const float4 q4 = *(const float4*)(q + (size_t)b * NN + m0 + tid * 4);
    const float sq[4] = { q4.x * sl2e, q4.y * sl2e, q4.z * sl2e, q4.w * sl2e };

    float acc[4][CPER];
    #pragma unroll
    for (int r = 0; r < 4; ++r)
        #pragma unroll
        for (int c = 0; c < CPER; ++c) acc[r][c] = 0.0f;

    #pragma unroll 2
    for (int g = 0; g < KQ; ++g) {
        const float4 kk = *(const float4*)(kbuf + g * 4);
        float s[4][4];
        #pragma unroll
        for (int r = 0; r < 4; ++r) {
            s[r][0] = __builtin_amdgcn_rcpf(1.0f + __builtin_amdgcn_exp2f(sq[r] * kk.x));
            s[r][1] = __builtin_amdgcn_rcpf(1.0f + __builtin_amdgcn_exp2f(sq[r] * kk.y));
            s[r][2] = __builtin_amdgcn_rcpf(1.0f + __builtin_amdgcn_exp2f(sq[r] * kk.z));
            s[r][3] = __builtin_amdgcn_rcpf(1.0f + __builtin_amdgcn_exp2f(sq[r] * kk.w));
        }
        #pragma unroll
        for (int c = 0; c < CPER; ++c) {
            const float4 vv = *(const float4*)(vbuf + c * KSEG + g * 4);  // broadcast
            #pragma unroll
            for (int r = 0; r < 4; ++r)
                acc[r][c] = fmaf(vv.x, s[r][0],
                            fmaf(vv.y, s[r][1],
                            fmaf(vv.z, s[r][2],
                            fmaf(vv.w, s[r][3], acc[r][c]))));
        }
    }

    // write partials: [branch][seg][b][c][m], float4 over m
    #pragma unroll
    for (int c = 0; c < CPER; ++c) {
        float4 o;
        o.x = acc[0][c]; o.y = acc[1][c]; o.z = acc[2][c]; o.w = acc[3][c];
        *(float4*)(pout + (((size_t)(branch * NSEG + seg) * BB + b) * C2 + c0 + c) * NN
                        + m0 + tid * 4) = o;
    }
}

// ---------------------------------------------------------------------------
// Stage C1: parallel segment reduction (generic in nseg).
// ---------------------------------------------------------------------------
__global__ __launch_bounds__(256) void reduce_kernel(float* __restrict__ p, int nseg)
{
    const int t      = blockIdx.x * 256 + threadIdx.x;
    const int m4     = t & 1023;
    const int c      = (t >> 10) & 31;
    const int b      = (t >> 15) & 1;
    const int branch = t >> 16;

    const size_t segstride = (size_t)BB * C2 * NN;
    const float* base = p + ((size_t)branch * nseg * BB + b) * C2 * NN
                          + (size_t)c * NN + m4 * 4;

    float4 acc = *(const float4*)base;
    for (int s = 1; s < nseg; ++s) {
        const float4 v = *(const float4*)(base + s * segstride);
        acc.x += v.x; acc.y += v.y; acc.z += v.z; acc.w += v.w;
    }
    *(float4*)(p + ((size_t)branch * nseg * BB + b) * C2 * NN
                 + (size_t)c * NN + m4 * 4) = acc;
}

// ---------------------------------------------------------------------------
// Stage C2: output conv + gamma + residual (unchanged).
// ---------------------------------------------------------------------------
__global__ __launch_bounds__(256) void conv_kernel(
    const float* __restrict__ x1, const float* __restrict__ x2,
    const float* __restrict__ wc1, const float* __restrict__ bc1,
    const float* __restrict__ wc2, const float* __restrict__ bc2,
    const float* __restrict__ g1,  const float* __restrict__ g2,
    const float* __restrict__ p,   float* __restrict__ out, int nseg)
{
    const int m      = blockIdx.x * 256 + threadIdx.x;
    const int co0    = blockIdx.y * 16;
    const int b      = blockIdx.z >> 1;
    const int branch = blockIdx.z & 1;

    const float* w; const float* bias; const float* x; float gamma; float* o;
    if (branch == 0) { w = wc2; bias = bc2; x = x1; gamma = g1[0]; o = out; }
    else             { w = wc1; bias = bc1; x = x2; gamma = g2[0]; o = out + (size_t)BB * CC * NN; }

    const float* sbase = p + ((size_t)branch * nseg * BB + b) * C2 * NN + m;
    float s[C2];
    #pragma unroll
    for (int c = 0; c < C2; ++c) s[c] = sbase[(size_t)c * NN];

    #pragma unroll
    for (int co = co0; co < co0 + 16; ++co) {
        float a = bias[co];
        #pragma unroll
        for (int c = 0; c < C2; ++c)
            a += w[co * C2 + c] * s[c];
        const size_t idx = ((size_t)b * CC + co) * NN + m;
        o[idx] = x[idx] + gamma * a;
    }
}

extern "C" void kernel_launch(void* const* d_in, const int* in_sizes, int n_in,
                              void* d_out, int out_size, void* d_ws, size_t ws_size,
                              hipStream_t stream)
{
    const float* x1  = (const float*)d_in[0];
    const float* x2  = (const float*)d_in[1];
    const float* wq1 = (const float*)d_in[2];
    const float* bq1 = (const float*)d_in[3];
    const float* wk1 = (const float*)d_in[4];
    const float* bk1 = (const float*)d_in[5];
    const float* wv1 = (const float*)d_in[6];
    const float* bv1 = (const float*)d_in[7];
    const float* wc1 = (const float*)d_in[8];
    const float* bc1 = (const float*)d_in[9];
    const float* wq2 = (const float*)d_in[10];
    const float* bq2 = (const float*)d_in[11];
    const float* wk2 = (const float*)d_in[12];
    const float* bk2 = (const float*)d_in[13];
    const float* wv2 = (const float*)d_in[14];
    const float* bv2 = (const float*)d_in[15];
    const float* wc2 = (const float*)d_in[16];
    const float* bc2 = (const float*)d_in[17];
    const float* g1  = (const float*)d_in[18];
    const float* g2  = (const float*)d_in[19];

    float* ws  = (float*)d_ws;
    float* out = (float*)d_out;

    proj_kernel<<<dim3(NN / 256, 6, BB), 256, 0, stream>>>(
        x1, x2, wq1, bq1, wk1, bk1, wv1, bv1,
        wq2, bq2, wk2, bk2, wv2, bv2, ws);

    const size_t need32 = ((size_t)WS_P + 2ull * 32 * BB * C2 * NN) * 4ull;
    const size_t need16 = ((size_t)WS_P + 2ull * 16 * BB * C2 * NN) * 4ull;

    const float* q1 = ws + WS_Q1; const float* k1 = ws + WS_K1;
    const float* q2 = ws + WS_Q2; const float* k2 = ws + WS_K2;
    const float* v1 = ws + WS_V1; const float* v2 = ws + WS_V2;
    float* pp = ws + WS_P;

    int nseg;
    if (ws_size >= need32) {
        nseg = 32;   // full C per block, 512 blocks = 2/CU
        attn_kernel<128, 32><<<dim3(NN / 1024, 32, 4), 256, 0, stream>>>(
            q1, k1, q2, k2, v1, v2, pp);
    } else if (ws_size >= need16) {
        nseg = 16;   // c-split, 512 blocks = 2/CU
        attn_kernel<256, 16><<<dim3(NN / 1024, 16, 8), 256, 0, stream>>>(
            q1, k1, q2, k2, v1, v2, pp);
    } else {
        nseg = 8;    // c-split 8 ways of nothing left: CPER=8, 512 blocks
        attn_kernel<512, 8><<<dim3(NN / 1024, 8, 16), 256, 0, stream>>>(
            q1, k1, q2, k2, v1, v2, pp);
    }

    reduce_kernel<<<dim3(512), 256, 0, stream>>>(pp, nseg);

    conv_kernel<<<dim3(NN / 256, 4, BB * 2), 256, 0, stream>>>(
        x1, x2, wc1, bc1, wc2, bc2, g1, g2, pp, out, nseg);
}

// Round 6
// 64.536 us; speedup vs baseline: 4.9487x; 1.7000x over previous
//
#include <hip/hip_runtime.h>

// Problem constants
#define NN 4096
#define CC 64
#define C2 32
#define BB 2

#define NSEG   8          // k-split across blocks
#define M_BLK  64         // m-tile per block
#define KBLK   64         // k per LDS tile
#define KB_ITERS (NN / NSEG / KBLK)

// Workspace layout (float offsets)
//   q1,k1,q2,k2 : [B][NN] f32
//   v1,v2       : [B][C2][NN] bf16 (ushort)  -> 131072 floats each
//   P           : [2][NSEG][B][C2][NN] f32 partials
#define WS_Q1 0
#define WS_K1 8192
#define WS_Q2 16384
#define WS_K2 24576
#define WS_V1 32768
#define WS_V2 163840
#define WS_P  294912

typedef __attribute__((address_space(1))) const unsigned int GUI;
typedef __attribute__((address_space(3))) unsigned int LUI;
typedef __attribute__((ext_vector_type(8))) short bf16x8;
typedef __attribute__((ext_vector_type(4))) float f32x4;

__device__ __forceinline__ void glds16(const void* g, void* l) {
    __builtin_amdgcn_global_load_lds((GUI*)g, (LUI*)l, 16, 0, 0);
}

__device__ __forceinline__ unsigned short bf16_rne(float f) {
    union { float f; unsigned u; } x; x.f = f;
    unsigned u = x.u + 0x7fff + ((x.u >> 16) & 1);
    return (unsigned short)(u >> 16);
}
__device__ __forceinline__ unsigned pack2(float a, float b) {
    return (unsigned)bf16_rne(a) | ((unsigned)bf16_rne(b) << 16);
}
__device__ __forceinline__ float sigm_e2(float x) {   // 1/(1+2^x)
    return __builtin_amdgcn_rcpf(1.0f + __builtin_amdgcn_exp2f(x));
}

// ---------------------------------------------------------------------------
// Stage A: 6 projections. v-projections now store bf16 (MFMA operand).
// ---------------------------------------------------------------------------
__global__ __launch_bounds__(256) void proj_kernel(
    const float* __restrict__ x1, const float* __restrict__ x2,
    const float* __restrict__ wq1, const float* __restrict__ bq1,
    const float* __restrict__ wk1, const float* __restrict__ bk1,
    const float* __restrict__ wv1, const float* __restrict__ bv1,
    const float* __restrict__ wq2, const float* __restrict__ bq2,
    const float* __restrict__ wk2, const float* __restrict__ bk2,
    const float* __restrict__ wv2, const float* __restrict__ bv2,
    float* __restrict__ ws)
{
    const int n = blockIdx.x * 256 + threadIdx.x;
    const int p = blockIdx.y;
    const int b = blockIdx.z;

    const float* x; const float* w; const float* bias;
    int mode; float* dstf; unsigned short* dstv;
    switch (p) {
      case 0: x = x1; w = wq1; bias = bq1; mode = 0; dstf = ws + WS_Q1; dstv = 0; break;
      case 1: x = x1; w = wk1; bias = bk1; mode = 0; dstf = ws + WS_K1; dstv = 0; break;
      case 2: x = x1; w = wv1; bias = bv1; mode = 2; dstf = 0; dstv = (unsigned short*)(ws + WS_V1); break;
      case 3: x = x2; w = wq2; bias = bq2; mode = 1; dstf = ws + WS_Q2; dstv = 0; break;
      case 4: x = x2; w = wk2; bias = bk2; mode = 1; dstf = ws + WS_K2; dstv = 0; break;
      default:x = x2; w = wv2; bias = bv2; mode = 2; dstf = 0; dstv = (unsigned short*)(ws + WS_V2); break;
    }

    float acc[C2];
    #pragma unroll
    for (int o = 0; o < C2; ++o) acc[o] = 0.0f;

    const float* xb = x + (size_t)b * CC * NN + n;
    for (int c = 0; c < CC; ++c) {
        const float xv = xb[(size_t)c * NN];
        #pragma unroll
        for (int o = 0; o < C2; ++o)
            acc[o] += w[o * CC + c] * xv;
    }
    #pragma unroll
    for (int o = 0; o < C2; ++o) acc[o] += bias[o];

    if (mode == 2) {
        #pragma unroll
        for (int o = 0; o < C2; ++o)
            dstv[((size_t)b * C2 + o) * NN + n] = bf16_rne(acc[o]);
    } else if (mode == 0) {
        float r = acc[0];
        #pragma unroll
        for (int o = 1; o < C2; ++o) r = fmaxf(r, acc[o]);
        dstf[(size_t)b * NN + n] = r;
    } else {
        float r = 0.0f;
        #pragma unroll
        for (int o = 0; o < C2; ++o) r += acc[o];
        dstf[(size_t)b * NN + n] = r * (1.0f / C2);
    }
}

// ---------------------------------------------------------------------------
// Stage B (MFMA): out[c,m] = sum_k V[c,k] * S[m,k],  S[m,k]=g(q[m]*k[k]).
// Block: 256 thr / 4 waves; owns (b,branch, m-tile=64, k-range=NN/NSEG).
// Per KBLK=64 iteration:
//   - V-tile (32c x 64k bf16) -> LDS via global_load_lds, source pre-swizzled
//   - S-tile (64m x 64k) computed in regs (sigmoid), packed bf16, ds_write
//     to XOR-swizzled [m][k] layout (slot ^= row&7) -> conflict-free b128.
//   - 4 waves = (c-tile 0/1) x (k-half 0/1): each wave 1 A-frag + 4 B-frags
//     + 4 MFMA 16x16x32_bf16 accumulating f32x4 acc[4 m-tiles].
// End: waves 2,3 dump acc to LDS; waves 0,1 add and store partials.
// ---------------------------------------------------------------------------
__global__ __launch_bounds__(256) void attn_mfma(
    const float* __restrict__ q1, const float* __restrict__ k1,
    const float* __restrict__ q2, const float* __restrict__ k2,
    const unsigned short* __restrict__ v1, const unsigned short* __restrict__ v2,
    float* __restrict__ pout)
{
    __shared__ unsigned short vtile[C2 * KBLK];     // 4 KB, rows c stride 128B
    __shared__ unsigned short stile[M_BLK * KBLK];  // 8 KB, rows m stride 128B

    const int tid = threadIdx.x;
    const int wv  = tid >> 6;
    const int ln  = tid & 63;

    const int seg    = blockIdx.y;
    const int z      = blockIdx.z;
    const int branch = z & 1;
    const int b      = z >> 1;
    const int m0     = blockIdx.x * M_BLK;
    const int kstart = seg * (NN / NSEG);

    const float* q; const float* kv; const unsigned short* vbf; float sl2e;
    if (branch == 0) { q = q1; kv = k2; vbf = v1; sl2e =  1.44269504089f; }
    else             { q = q2; kv = k1; vbf = v2; sl2e = -1.44269504089f; }

    const float qs = q[(size_t)b * NN + m0 + ln] * sl2e;   // this thread's m-row

    f32x4 acc[4];
    #pragma unroll
    for (int mt = 0; mt < 4; ++mt) acc[mt] = (f32x4){0.f, 0.f, 0.f, 0.f};

    // per-thread V staging source (pre-swizzled global so LDS dest is linear)
    const int vc   = tid >> 3;            // c row 0..31
    const int vs   = tid & 7;             // dest slot 0..7
    const unsigned short* vsrc0 = vbf + (size_t)(b * C2 + vc) * NN
                                + ((vs ^ (vc & 7)) << 3);

    for (int kb = 0; kb < KB_ITERS; ++kb) {
        const int k0 = kstart + kb * KBLK;

        // ---- stage V-tile (async, lane-linear dest) ----
        glds16(vsrc0 + k0, (char*)vtile + tid * 16);

        // ---- compute S-tile: this thread does row m=ln, k = [wv*16, wv*16+16) ----
        const float* kvp = kv + (size_t)b * NN + k0 + (wv << 4);
        const float4 ka = *(const float4*)(kvp);
        const float4 kb4 = *(const float4*)(kvp + 4);
        const float4 kc = *(const float4*)(kvp + 8);
        const float4 kd = *(const float4*)(kvp + 12);

        float s[16];
        s[0]  = sigm_e2(qs * ka.x);  s[1]  = sigm_e2(qs * ka.y);
        s[2]  = sigm_e2(qs * ka.z);  s[3]  = sigm_e2(qs * ka.w);
        s[4]  = sigm_e2(qs * kb4.x); s[5]  = sigm_e2(qs * kb4.y);
        s[6]  = sigm_e2(qs * kb4.z); s[7]  = sigm_e2(qs * kb4.w);
        s[8]  = sigm_e2(qs * kc.x);  s[9]  = sigm_e2(qs * kc.y);
        s[10] = sigm_e2(qs * kc.z);  s[11] = sigm_e2(qs * kc.w);
        s[12] = sigm_e2(qs * kd.x);  s[13] = sigm_e2(qs * kd.y);
        s[14] = sigm_e2(qs * kd.z);  s[15] = sigm_e2(qs * kd.w);

        uint4 w0, w1;
        w0.x = pack2(s[0],  s[1]);  w0.y = pack2(s[2],  s[3]);
        w0.z = pack2(s[4],  s[5]);  w0.w = pack2(s[6],  s[7]);
        w1.x = pack2(s[8],  s[9]);  w1.y = pack2(s[10], s[11]);
        w1.z = pack2(s[12], s[13]); w1.w = pack2(s[14], s[15]);

        char* srow = (char*)stile + ln * 128;
        *(uint4*)(srow + ((((wv << 1) | 0) ^ (ln & 7)) << 4)) = w0;
        *(uint4*)(srow + ((((wv << 1) | 1) ^ (ln & 7)) << 4)) = w1;

        asm volatile("s_waitcnt vmcnt(0)" ::: "memory");
        __syncthreads();

        // ---- MFMA: wave = (c-tile = wv&1, k-half = wv>>1) ----
        const int ct  = wv & 1;
        const int ks  = wv >> 1;
        const int col = (ks << 2) + (ln >> 4);       // col16 index before XOR
        const int ac  = ct * 16 + (ln & 15);         // V row (c)
        const bf16x8 af = *(const bf16x8*)((const char*)vtile
                          + ac * 128 + ((col ^ (ac & 7)) << 4));
        #pragma unroll
        for (int mt = 0; mt < 4; ++mt) {
            const int bm = mt * 16 + (ln & 15);      // S row (m)
            const bf16x8 bfr = *(const bf16x8*)((const char*)stile
                               + bm * 128 + ((col ^ (bm & 7)) << 4));
            acc[mt] = __builtin_amdgcn_mfma_f32_16x16x32_bf16(af, bfr, acc[mt], 0, 0, 0);
        }
        __syncthreads();
    }

    // ---- cross-wave k-half reduction (reuse stile as f32 scratch) ----
    float* red = (float*)stile;
    if (wv >= 2) {
        #pragma unroll
        for (int mt = 0; mt < 4; ++mt)
            *(f32x4*)&red[((wv - 2) * 4 + mt) * 256 + ln * 4] = acc[mt];
    }
    __syncthreads();
    if (wv < 2) {
        const size_t obase = (((size_t)(branch * NSEG + seg) * BB + b) * C2) * NN;
        #pragma unroll
        for (int mt = 0; mt < 4; ++mt) {
            const f32x4 o = *(const f32x4*)&red[(wv * 4 + mt) * 256 + ln * 4];
            acc[mt].x += o.x; acc[mt].y += o.y; acc[mt].z += o.z; acc[mt].w += o.w;
            #pragma unroll
            for (int j = 0; j < 4; ++j) {
                const int c = wv * 16 + (ln >> 4) * 4 + j;
                const int m = m0 + mt * 16 + (ln & 15);
                pout[obase + (size_t)c * NN + m] = acc[mt][j];
            }
        }
    }
}

// ---------------------------------------------------------------------------
// Stage C1: parallel segment reduction (in-place into seg-0 slot).
// ---------------------------------------------------------------------------
__global__ __launch_bounds__(256) void reduce_kernel(float* __restrict__ p, int nseg)
{
    const int t      = blockIdx.x * 256 + threadIdx.x;
    const int m4     = t & 1023;
    const int c      = (t >> 10) & 31;
    const int b      = (t >> 15) & 1;
    const int branch = t >> 16;

    const size_t segstride = (size_t)BB * C2 * NN;
    const float* base = p + ((size_t)branch * nseg * BB + b) * C2 * NN
                          + (size_t)c * NN + m4 * 4;

    float4 acc = *(const float4*)base;
    for (int s = 1; s < nseg; ++s) {
        const float4 v = *(const float4*)(base + s * segstride);
        acc.x += v.x; acc.y += v.y; acc.z += v.z; acc.w += v.w;
    }
    *(float4*)(p + ((size_t)branch * nseg * BB + b) * C2 * NN
                 + (size_t)c * NN + m4 * 4) = acc;
}

// ---------------------------------------------------------------------------
// Stage C2: output 1x1 conv + gamma + residual.
// ---------------------------------------------------------------------------
__global__ __launch_bounds__(256) void conv_kernel(
    const float* __restrict__ x1, const float* __restrict__ x2,
    const float* __restrict__ wc1, const float* __restrict__ bc1,
    const float* __restrict__ wc2, const float* __restrict__ bc2,
    const float* __restrict__ g1,  const float* __restrict__ g2,
    const float* __restrict__ p,   float* __restrict__ out, int nseg)
{
    const int m      = blockIdx.x * 256 + threadIdx.x;
    const int co0    = blockIdx.y * 16;
    const int b      = blockIdx.z >> 1;
    const int branch = blockIdx.z & 1;

    const float* w; const float* bias; const float* x; float gamma; float* o;
    if (branch == 0) { w = wc2; bias = bc2; x = x1; gamma = g1[0]; o = out; }
    else             { w = wc1; bias = bc1; x = x2; gamma = g2[0]; o = out + (size_t)BB * CC * NN; }

    const float* sbase = p + ((size_t)branch * nseg * BB + b) * C2 * NN + m;
    float s[C2];
    #pragma unroll
    for (int c = 0; c < C2; ++c) s[c] = sbase[(size_t)c * NN];

    #pragma unroll
    for (int co = co0; co < co0 + 16; ++co) {
        float a = bias[co];
        #pragma unroll
        for (int c = 0; c < C2; ++c)
            a += w[co * C2 + c] * s[c];
        const size_t idx = ((size_t)b * CC + co) * NN + m;
        o[idx] = x[idx] + gamma * a;
    }
}

extern "C" void kernel_launch(void* const* d_in, const int* in_sizes, int n_in,
                              void* d_out, int out_size, void* d_ws, size_t ws_size,
                              hipStream_t stream)
{
    const float* x1  = (const float*)d_in[0];
    const float* x2  = (const float*)d_in[1];
    const float* wq1 = (const float*)d_in[2];
    const float* bq1 = (const float*)d_in[3];
    const float* wk1 = (const float*)d_in[4];
    const float* bk1 = (const float*)d_in[5];
    const float* wv1 = (const float*)d_in[6];
    const float* bv1 = (const float*)d_in[7];
    const float* wc1 = (const float*)d_in[8];
    const float* bc1 = (const float*)d_in[9];
    const float* wq2 = (const float*)d_in[10];
    const float* bq2 = (const float*)d_in[11];
    const float* wk2 = (const float*)d_in[12];
    const float* bk2 = (const float*)d_in[13];
    const float* wv2 = (const float*)d_in[14];
    const float* bv2 = (const float*)d_in[15];
    const float* wc2 = (const float*)d_in[16];
    const float* bc2 = (const float*)d_in[17];
    const float* g1  = (const float*)d_in[18];
    const float* g2  = (const float*)d_in[19];

    float* ws  = (float*)d_ws;
    float* out = (float*)d_out;

    proj_kernel<<<dim3(NN / 256, 6, BB), 256, 0, stream>>>(
        x1, x2, wq1, bq1, wk1, bk1, wv1, bv1,
        wq2, bq2, wk2, bk2, wv2, bv2, ws);

    const float* q1 = ws + WS_Q1; const float* k1 = ws + WS_K1;
    const float* q2 = ws + WS_Q2; const float* k2 = ws + WS_K2;
    const unsigned short* v1 = (const unsigned short*)(ws + WS_V1);
    const unsigned short* v2 = (const unsigned short*)(ws + WS_V2);
    float* pp = ws + WS_P;

    attn_mfma<<<dim3(NN / M_BLK, NSEG, BB * 2), 256, 0, stream>>>(
        q1, k1, q2, k2, v1, v2, pp);

    reduce_kernel<<<dim3(512), 256, 0, stream>>>(pp, NSEG);

    conv_kernel<<<dim3(NN / 256, 4, BB * 2), 256, 0, stream>>>(
        x1, x2, wc1, bc1, wc2, bc2, g1, g2, pp, out, NSEG);
}

// Round 7
// 56.701 us; speedup vs baseline: 5.6325x; 1.1382x over previous
//
#include <hip/hip_runtime.h>

// Problem constants
#define NN 4096
#define CC 64
#define C2 32
#define BB 2

#define NSEG   4          // k-split across blocks
#define M_BLK  64         // m-tile per block
#define KBLK   64         // k per LDS tile
#define KB_ITERS (NN / NSEG / KBLK)

// Workspace layout (float offsets)
//   q1,k1,q2,k2 : [B][NN] f32
//   v1,v2       : [B][C2][NN] bf16 (ushort)  -> 131072 floats each
//   P           : [2][NSEG][B][C2][NN] f32 partials
#define WS_Q1 0
#define WS_K1 8192
#define WS_Q2 16384
#define WS_K2 24576
#define WS_V1 32768
#define WS_V2 163840
#define WS_P  294912

typedef __attribute__((address_space(1))) const unsigned int GUI;
typedef __attribute__((address_space(3))) unsigned int LUI;
typedef __attribute__((ext_vector_type(8))) short bf16x8;
typedef __attribute__((ext_vector_type(4))) float f32x4;

__device__ __forceinline__ void glds16(const void* g, void* l) {
    __builtin_amdgcn_global_load_lds((GUI*)g, (LUI*)l, 16, 0, 0);
}

__device__ __forceinline__ unsigned short bf16_rne(float f) {
    union { float f; unsigned u; } x; x.f = f;
    unsigned u = x.u + 0x7fff + ((x.u >> 16) & 1);
    return (unsigned short)(u >> 16);
}
__device__ __forceinline__ unsigned pack2(float a, float b) {
    return (unsigned)bf16_rne(a) | ((unsigned)bf16_rne(b) << 16);
}
__device__ __forceinline__ float sigm_e2(float x) {   // 1/(1+2^x)
    return __builtin_amdgcn_rcpf(1.0f + __builtin_amdgcn_exp2f(x));
}

// ---------------------------------------------------------------------------
// Stage A v2: 6 projections, input-channel sum split across 4 wave-groups.
// Block = 256 thr = 64 n x 4 c-quarters (16 input ch each); LDS tree-reduce.
// Grid (NN/64, 6, B) = 768 blocks = 3 blocks/CU (r6 had 192 = 0.75/CU).
// ---------------------------------------------------------------------------
__global__ __launch_bounds__(256) void proj_kernel(
    const float* __restrict__ x1, const float* __restrict__ x2,
    const float* __restrict__ wq1, const float* __restrict__ bq1,
    const float* __restrict__ wk1, const float* __restrict__ bk1,
    const float* __restrict__ wv1, const float* __restrict__ bv1,
    const float* __restrict__ wq2, const float* __restrict__ bq2,
    const float* __restrict__ wk2, const float* __restrict__ bk2,
    const float* __restrict__ wv2, const float* __restrict__ bv2,
    float* __restrict__ ws)
{
    const int ln = threadIdx.x & 63;          // local n
    const int og = threadIdx.x >> 6;          // input-channel quarter 0..3
    const int n  = blockIdx.x * 64 + ln;
    const int p  = blockIdx.y;
    const int b  = blockIdx.z;

    const float* x; const float* w; const float* bias;
    int mode; float* dstf; unsigned short* dstv;
    switch (p) {
      case 0: x = x1; w = wq1; bias = bq1; mode = 0; dstf = ws + WS_Q1; dstv = 0; break;
      case 1: x = x1; w = wk1; bias = bk1; mode = 0; dstf = ws + WS_K1; dstv = 0; break;
      case 2: x = x1; w = wv1; bias = bv1; mode = 2; dstf = 0; dstv = (unsigned short*)(ws + WS_V1); break;
      case 3: x = x2; w = wq2; bias = bq2; mode = 1; dstf = ws + WS_Q2; dstv = 0; break;
      case 4: x = x2; w = wk2; bias = bk2; mode = 1; dstf = ws + WS_K2; dstv = 0; break;
      default:x = x2; w = wv2; bias = bv2; mode = 2; dstf = 0; dstv = (unsigned short*)(ws + WS_V2); break;
    }

    __shared__ float red[4][C2][64];          // 32 KB

    float acc[C2];
    #pragma unroll
    for (int o = 0; o < C2; ++o) acc[o] = 0.0f;

    const float* xb = x + ((size_t)b * CC + og * 16) * NN + n;
    #pragma unroll
    for (int ci = 0; ci < 16; ++ci) {
        const float xv = xb[(size_t)ci * NN];              // coalesced
        #pragma unroll
        for (int o = 0; o < C2; ++o)
            acc[o] += w[o * CC + og * 16 + ci] * xv;       // wave-uniform
    }
    #pragma unroll
    for (int o = 0; o < C2; ++o) red[og][o][ln] = acc[o];
    __syncthreads();

    // combine quarters: this thread finishes outputs o in [og*8, og*8+8)
    float f[8];
    #pragma unroll
    for (int j = 0; j < 8; ++j) {
        const int o = og * 8 + j;
        f[j] = red[0][o][ln] + red[1][o][ln] + red[2][o][ln] + red[3][o][ln]
             + bias[o];
    }

    if (mode == 2) {
        #pragma unroll
        for (int j = 0; j < 8; ++j)
            dstv[((size_t)b * C2 + og * 8 + j) * NN + n] = bf16_rne(f[j]);
    } else {
        float r;
        if (mode == 0) {
            r = f[0];
            #pragma unroll
            for (int j = 1; j < 8; ++j) r = fmaxf(r, f[j]);
        } else {
            r = 0.0f;
            #pragma unroll
            for (int j = 0; j < 8; ++j) r += f[j];
        }
        __syncthreads();                       // LDS reuse
        red[og][0][ln] = r;
        __syncthreads();
        if (og == 0) {
            const float a0 = red[0][0][ln], a1 = red[1][0][ln];
            const float a2 = red[2][0][ln], a3 = red[3][0][ln];
            const float rr = (mode == 0)
                ? fmaxf(fmaxf(a0, a1), fmaxf(a2, a3))
                : (a0 + a1 + a2 + a3) * (1.0f / C2);
            dstf[(size_t)b * NN + n] = rr;
        }
    }
}

// ---------------------------------------------------------------------------
// Stage B (MFMA): unchanged core from r6; NSEG 8->4 (grid 1024 = 4 blocks/CU,
// partial traffic halves).
// ---------------------------------------------------------------------------
__global__ __launch_bounds__(256) void attn_mfma(
    const float* __restrict__ q1, const float* __restrict__ k1,
    const float* __restrict__ q2, const float* __restrict__ k2,
    const unsigned short* __restrict__ v1, const unsigned short* __restrict__ v2,
    float* __restrict__ pout)
{
    __shared__ unsigned short vtile[C2 * KBLK];     // 4 KB
    __shared__ unsigned short stile[M_BLK * KBLK];  // 8 KB

    const int tid = threadIdx.x;
    const int wv  = tid >> 6;
    const int ln  = tid & 63;

    const int seg    = blockIdx.y;
    const int z      = blockIdx.z;
    const int branch = z & 1;
    const int b      = z >> 1;
    const int m0     = blockIdx.x * M_BLK;
    const int kstart = seg * (NN / NSEG);

    const float* q; const float* kv; const unsigned short* vbf; float sl2e;
    if (branch == 0) { q = q1; kv = k2; vbf = v1; sl2e =  1.44269504089f; }
    else             { q = q2; kv = k1; vbf = v2; sl2e = -1.44269504089f; }

    const float qs = q[(size_t)b * NN + m0 + ln] * sl2e;

    f32x4 acc[4];
    #pragma unroll
    for (int mt = 0; mt < 4; ++mt) acc[mt] = (f32x4){0.f, 0.f, 0.f, 0.f};

    const int vc = tid >> 3;
    const int vs = tid & 7;
    const unsigned short* vsrc0 = vbf + (size_t)(b * C2 + vc) * NN
                                + ((vs ^ (vc & 7)) << 3);

    for (int kb = 0; kb < KB_ITERS; ++kb) {
        const int k0 = kstart + kb * KBLK;

        glds16(vsrc0 + k0, (char*)vtile + tid * 16);

        const float* kvp = kv + (size_t)b * NN + k0 + (wv << 4);
        const float4 ka = *(const float4*)(kvp);
        const float4 kb4 = *(const float4*)(kvp + 4);
        const float4 kc = *(const float4*)(kvp + 8);
        const float4 kd = *(const float4*)(kvp + 12);

        float s[16];
        s[0]  = sigm_e2(qs * ka.x);  s[1]  = sigm_e2(qs * ka.y);
        s[2]  = sigm_e2(qs * ka.z);  s[3]  = sigm_e2(qs * ka.w);
        s[4]  = sigm_e2(qs * kb4.x); s[5]  = sigm_e2(qs * kb4.y);
        s[6]  = sigm_e2(qs * kb4.z); s[7]  = sigm_e2(qs * kb4.w);
        s[8]  = sigm_e2(qs * kc.x);  s[9]  = sigm_e2(qs * kc.y);
        s[10] = sigm_e2(qs * kc.z);  s[11] = sigm_e2(qs * kc.w);
        s[12] = sigm_e2(qs * kd.x);  s[13] = sigm_e2(qs * kd.y);
        s[14] = sigm_e2(qs * kd.z);  s[15] = sigm_e2(qs * kd.w);

        uint4 w0, w1;
        w0.x = pack2(s[0],  s[1]);  w0.y = pack2(s[2],  s[3]);
        w0.z = pack2(s[4],  s[5]);  w0.w = pack2(s[6],  s[7]);
        w1.x = pack2(s[8],  s[9]);  w1.y = pack2(s[10], s[11]);
        w1.z = pack2(s[12], s[13]); w1.w = pack2(s[14], s[15]);

        char* srow = (char*)stile + ln * 128;
        *(uint4*)(srow + ((((wv << 1) | 0) ^ (ln & 7)) << 4)) = w0;
        *(uint4*)(srow + ((((wv << 1) | 1) ^ (ln & 7)) << 4)) = w1;

        asm volatile("s_waitcnt vmcnt(0)" ::: "memory");
        __syncthreads();

        const int ct  = wv & 1;
        const int ks  = wv >> 1;
        const int col = (ks << 2) + (ln >> 4);
        const int ac  = ct * 16 + (ln & 15);
        const bf16x8 af = *(const bf16x8*)((const char*)vtile
                          + ac * 128 + ((col ^ (ac & 7)) << 4));
        #pragma unroll
        for (int mt = 0; mt < 4; ++mt) {
            const int bm = mt * 16 + (ln & 15);
            const bf16x8 bfr = *(const bf16x8*)((const char*)stile
                               + bm * 128 + ((col ^ (bm & 7)) << 4));
            acc[mt] = __builtin_amdgcn_mfma_f32_16x16x32_bf16(af, bfr, acc[mt], 0, 0, 0);
        }
        __syncthreads();
    }

    float* red = (float*)stile;
    if (wv >= 2) {
        #pragma unroll
        for (int mt = 0; mt < 4; ++mt)
            *(f32x4*)&red[((wv - 2) * 4 + mt) * 256 + ln * 4] = acc[mt];
    }
    __syncthreads();
    if (wv < 2) {
        const size_t obase = (((size_t)(branch * NSEG + seg) * BB + b) * C2) * NN;
        #pragma unroll
        for (int mt = 0; mt < 4; ++mt) {
            const f32x4 o = *(const f32x4*)&red[(wv * 4 + mt) * 256 + ln * 4];
            acc[mt].x += o.x; acc[mt].y += o.y; acc[mt].z += o.z; acc[mt].w += o.w;
            #pragma unroll
            for (int j = 0; j < 4; ++j) {
                const int c = wv * 16 + (ln >> 4) * 4 + j;
                const int m = m0 + mt * 16 + (ln & 15);
                pout[obase + (size_t)c * NN + m] = acc[mt][j];
            }
        }
    }
}

// ---------------------------------------------------------------------------
// Stage C1: parallel segment reduction (in-place into seg-0 slot).
// ---------------------------------------------------------------------------
__global__ __launch_bounds__(256) void reduce_kernel(float* __restrict__ p, int nseg)
{
    const int t      = blockIdx.x * 256 + threadIdx.x;
    const int m4     = t & 1023;
    const int c      = (t >> 10) & 31;
    const int b      = (t >> 15) & 1;
    const int branch = t >> 16;

    const size_t segstride = (size_t)BB * C2 * NN;
    const float* base = p + ((size_t)branch * nseg * BB + b) * C2 * NN
                          + (size_t)c * NN + m4 * 4;

    float4 acc = *(const float4*)base;
    for (int s = 1; s < nseg; ++s) {
        const float4 v = *(const float4*)(base + s * segstride);
        acc.x += v.x; acc.y += v.y; acc.z += v.z; acc.w += v.w;
    }
    *(float4*)(p + ((size_t)branch * nseg * BB + b) * C2 * NN
                 + (size_t)c * NN + m4 * 4) = acc;
}

// ---------------------------------------------------------------------------
// Stage C2: output conv + gamma + residual. co-split 8 -> 512 blocks (2/CU).
// ---------------------------------------------------------------------------
__global__ __launch_bounds__(256) void conv_kernel(
    const float* __restrict__ x1, const float* __restrict__ x2,
    const float* __restrict__ wc1, const float* __restrict__ bc1,
    const float* __restrict__ wc2, const float* __restrict__ bc2,
    const float* __restrict__ g1,  const float* __restrict__ g2,
    const float* __restrict__ p,   float* __restrict__ out, int nseg)
{
    const int m      = blockIdx.x * 256 + threadIdx.x;
    const int co0    = blockIdx.y * 8;
    const int b      = blockIdx.z >> 1;
    const int branch = blockIdx.z & 1;

    const float* w; const float* bias; const float* x; float gamma; float* o;
    if (branch == 0) { w = wc2; bias = bc2; x = x1; gamma = g1[0]; o = out; }
    else             { w = wc1; bias = bc1; x = x2; gamma = g2[0]; o = out + (size_t)BB * CC * NN; }

    const float* sbase = p + ((size_t)branch * nseg * BB + b) * C2 * NN + m;
    float s[C2];
    #pragma unroll
    for (int c = 0; c < C2; ++c) s[c] = sbase[(size_t)c * NN];

    #pragma unroll
    for (int co = co0; co < co0 + 8; ++co) {
        float a = bias[co];
        #pragma unroll
        for (int c = 0; c < C2; ++c)
            a += w[co * C2 + c] * s[c];
        const size_t idx = ((size_t)b * CC + co) * NN + m;
        o[idx] = x[idx] + gamma * a;
    }
}

extern "C" void kernel_launch(void* const* d_in, const int* in_sizes, int n_in,
                              void* d_out, int out_size, void* d_ws, size_t ws_size,
                              hipStream_t stream)
{
    const float* x1  = (const float*)d_in[0];
    const float* x2  = (const float*)d_in[1];
    const float* wq1 = (const float*)d_in[2];
    const float* bq1 = (const float*)d_in[3];
    const float* wk1 = (const float*)d_in[4];
    const float* bk1 = (const float*)d_in[5];
    const float* wv1 = (const float*)d_in[6];
    const float* bv1 = (const float*)d_in[7];
    const float* wc1 = (const float*)d_in[8];
    const float* bc1 = (const float*)d_in[9];
    const float* wq2 = (const float*)d_in[10];
    const float* bq2 = (const float*)d_in[11];
    const float* wk2 = (const float*)d_in[12];
    const float* bk2 = (const float*)d_in[13];
    const float* wv2 = (const float*)d_in[14];
    const float* bv2 = (const float*)d_in[15];
    const float* wc2 = (const float*)d_in[16];
    const float* bc2 = (const float*)d_in[17];
    const float* g1  = (const float*)d_in[18];
    const float* g2  = (const float*)d_in[19];

    float* ws  = (float*)d_ws;
    float* out = (float*)d_out;

    proj_kernel<<<dim3(NN / 64, 6, BB), 256, 0, stream>>>(
        x1, x2, wq1, bq1, wk1, bk1, wv1, bv1,
        wq2, bq2, wk2, bk2, wv2, bv2, ws);

    const float* q1 = ws + WS_Q1; const float* k1 = ws + WS_K1;
    const float* q2 = ws + WS_Q2; const float* k2 = ws + WS_K2;
    const unsigned short* v1 = (const unsigned short*)(ws + WS_V1);
    const unsigned short* v2 = (const unsigned short*)(ws + WS_V2);
    float* pp = ws + WS_P;

    attn_mfma<<<dim3(NN / M_BLK, NSEG, BB * 2), 256, 0, stream>>>(
        q1, k1, q2, k2, v1, v2, pp);

    reduce_kernel<<<dim3(512), 256, 0, stream>>>(pp, NSEG);

    conv_kernel<<<dim3(NN / 256, 8, BB * 2), 256, 0, stream>>>(
        x1, x2, wc1, bc1, wc2, bc2, g1, g2, pp, out, NSEG);
}